// Round 19
// baseline (38.238 us; speedup 1.0000x reference)
//
#include <hip/hip_runtime.h>
#include <hip/hip_bf16.h>

typedef __attribute__((ext_vector_type(4))) float f32x4;
typedef __attribute__((ext_vector_type(2))) float f32x2;
typedef __attribute__((ext_vector_type(4))) int i32x4;
typedef __attribute__((ext_vector_type(8))) int i32x8;

constexpr int P = 8192, C = 8192, D = 256;
constexpr int DB = D / 2;   // 128 bytes per packed fp4 row

__device__ __forceinline__ void gload_lds16(const void* g, void* l) {
    __builtin_amdgcn_global_load_lds((const __attribute__((address_space(1))) void*)g,
                                     (__attribute__((address_space(3))) void*)l, 16, 0, 0);
}

// fp4 e2m1 RTN encode of t in +/-[0,6]; grid {0,.5,1,1.5,2,3,4,6}.
__device__ __forceinline__ unsigned int q4(float t) {
    const float a = fabsf(t);
    unsigned int c = (a >= 0.25f) + (a >= 0.75f) + (a >= 1.25f) + (a >= 1.75f)
                   + (a >= 2.5f) + (a >= 3.5f) + (a >= 5.0f);
    return c | (t < 0.f ? 8u : 0u);
}

// Normalize rows to unit L2, scale x8, store packed fp4 e2m1 (2/byte).
// Block 0 thread 0 also zeroes the gemm's done-counter (ws is poisoned 0xAA
// once and never re-poisoned; stream order makes this visible to gemm).
__global__ __launch_bounds__(256) void prep_kernel(const float* __restrict__ prev,
                                                   const float* __restrict__ cur,
                                                   unsigned char* __restrict__ prevb,
                                                   unsigned char* __restrict__ curb,
                                                   unsigned int* __restrict__ counter) {
    if (blockIdx.x == 0 && threadIdx.x == 0)
        __hip_atomic_store(counter, 0u, __ATOMIC_RELAXED, __HIP_MEMORY_SCOPE_AGENT);
    const int lane = threadIdx.x & 63;
    const int wv = threadIdx.x >> 6;
    const int row = blockIdx.x * 4 + wv;
    const float* src;
    unsigned char* dst;
    int r;
    if (row < P) { src = prev; dst = prevb; r = row; }
    else         { src = cur;  dst = curb;  r = row - P; }
    const float4 v = *(const float4*)(src + (size_t)r * D + lane * 4);
    float ss = v.x * v.x + v.y * v.y + v.z * v.z + v.w * v.w;
#pragma unroll
    for (int off = 32; off; off >>= 1) ss += __shfl_xor(ss, off, 64);
    const float s8 = 8.0f / sqrtf(ss);
    const unsigned int b0 = q4(v.x * s8) | (q4(v.y * s8) << 4);
    const unsigned int b1 = q4(v.z * s8) | (q4(v.w * s8) << 4);
    ((unsigned short*)(dst + (size_t)r * DB))[lane] = (unsigned short)(b0 | (b1 << 8));
}

// fmt 4 = fp4 both operands; scale bytes 0x7C = 2^-3 (E8M0 124).
#define MFMA_SC4(A, B, ACC) \
    __builtin_amdgcn_mfma_scale_f32_16x16x128_f8f6f4( \
        (A), (B), (ACC), 4, 4, 0, 0x7C7C7C7C, 0, 0x7C7C7C7C)

// r18 stage-once fp4 GEMM + (a) cid loads hoisted pre-loop (main loop has
// ZERO vmem/barriers/waitcnts: pure {4 ds_read -> 32 MFMA -> VALU epilogue})
// and (b) fused deterministic final reduction: each block publishes its
// partial with an agent-scope atomic store; the LAST block (device-scope
// counter) re-reads all 256 partials with agent-scope atomic loads (dodges
// cross-XCD L2 staleness) and sums them in FIXED index order in double ->
// bitwise-deterministic output, third kernel launch eliminated.
__global__ __attribute__((amdgpu_flat_work_group_size(512, 512), amdgpu_waves_per_eu(2, 2)))
void gemm_bce_kernel(
    const unsigned char* __restrict__ Ab, const unsigned char* __restrict__ Bb,
    const int* __restrict__ pids, const int* __restrict__ cids,
    float* __restrict__ partial, unsigned int* __restrict__ counter,
    float* __restrict__ out) {
    __shared__ unsigned char sA[32768];        // 256 rows x 128 B; later tile-7 B
    __shared__ unsigned char sB[7][16384];     // 128 cols x 128 B per tile
    __shared__ float bsums[8];
    __shared__ double red[8];
    __shared__ int amlast;

    const int tid = threadIdx.x;
    const int lane = tid & 63;
    const int wv = tid >> 6;
    const int wm = wv >> 2, wn = wv & 3;       // 2M x 4N; wave tile 128x32
    const int fr = lane & 15, fq = lane >> 4;
    const int bid = blockIdx.x;
    const int cslab = (bid & 7) * 1024;        // XCD col-slab
    const int pblock = (bid >> 3) * 256;

    auto stageA = [&]() {
#pragma unroll
        for (int i = 0; i < 4; ++i) {
            const int G = i * 512 + tid;       // 2048 granules = 256 rows x 8
            const int row = G >> 3, g = G & 7;
            gload_lds16(Ab + (size_t)(pblock + row) * DB + ((g ^ (row & 7)) * 16),
                        &sA[G * 16]);
        }
    };
    auto stageB = [&](int t, unsigned char* dst) {
#pragma unroll
        for (int i = 0; i < 2; ++i) {
            const int G = i * 512 + tid;       // 1024 granules = 128 cols x 8
            const int col = G >> 3, g = G & 7;
            gload_lds16(Bb + (size_t)(cslab + t * 128 + col) * DB + ((g ^ (col & 7)) * 16),
                        dst + G * 16);
        }
    };

    // ids packed 2/reg (ids < 16384). pid rows: wm*128+m*16+fq*4+reg.
    int pidp[16];
#pragma unroll
    for (int m = 0; m < 8; ++m)
#pragma unroll
        for (int rp = 0; rp < 2; ++rp) {
            const int base = pblock + wm * 128 + m * 16 + fq * 4 + rp * 2;
            pidp[m * 2 + rp] = (pids[base] & 0xffff) | (pids[base + 1] << 16);
        }
    int cidp[8];   // per tile: cols wn*32+{0,16}+fr packed lo|hi
#pragma unroll
    for (int t = 0; t < 8; ++t) {
        const int c0 = cslab + t * 128 + wn * 32 + fr;
        cidp[t] = (cids[c0] & 0xffff) | (cids[c0 + 16] << 16);
    }

    stageA();
#pragma unroll
    for (int t = 0; t < 7; ++t) stageB(t, &sB[t][0]);
    __syncthreads();                 // ONE drain: ids + A + B0..6 all landed

    // ---- A fragments: LDS -> regs ONCE (payload lo half, hi duplicated) ----
    i32x8 afr[8][2];
#pragma unroll
    for (int m = 0; m < 8; ++m)
#pragma unroll
        for (int kt = 0; kt < 2; ++kt) {
            const int row = wm * 128 + m * 16 + fr;
            const int g = kt * 4 + fq;
            const i32x4 lo = *(const i32x4*)&sA[row * DB + ((g ^ (row & 7)) * 16)];
            afr[m][kt] = __builtin_shufflevector(lo, lo, 0, 1, 2, 3, 0, 1, 2, 3);
        }
    __syncthreads();                 // sA reads done -> safe to overwrite
    stageB(7, &sA[0]);               // tile 7 into dead sA (lands during t0..6)

    constexpr float C1 = 0.125f, C2 = -5.2083333e-3f, C3 = 3.4722222e-4f, C4 = -2.6354832e-5f;
    f32x2 sh2 = {0.f, 0.f}, sx2 = {0.f, 0.f};

    auto tileBody = [&](int t, const unsigned char* pb) {
        i32x8 bfr[2][2];
#pragma unroll
        for (int n = 0; n < 2; ++n)
#pragma unroll
            for (int kt = 0; kt < 2; ++kt) {
                const int col = wn * 32 + n * 16 + fr;
                const int g = kt * 4 + fq;
                const i32x4 lo = *(const i32x4*)&pb[col * DB + ((g ^ (col & 7)) * 16)];
                bfr[n][kt] = __builtin_shufflevector(lo, lo, 0, 1, 2, 3, 0, 1, 2, 3);
            }
        f32x4 acc[8][2] = {};
        __builtin_amdgcn_s_setprio(1);
#pragma unroll
        for (int kt = 0; kt < 2; ++kt)
#pragma unroll
            for (int m = 0; m < 8; ++m)
#pragma unroll
                for (int n = 0; n < 2; ++n)
                    acc[m][n] = MFMA_SC4(afr[m][kt], bfr[n][kt], acc[m][n]);
        __builtin_amdgcn_s_setprio(0);

        const int cp = cidp[t];
        const int clo = cp & 0xffff, chi = (int)((unsigned)cp >> 16);
        // fused BCE epilogue (C/D: col=lane&15, row=fq*4+reg, m89-verified)
#pragma unroll
        for (int m = 0; m < 8; ++m)
#pragma unroll
            for (int n = 0; n < 2; ++n)
#pragma unroll
                for (int rp = 0; rp < 2; ++rp) {
                    const f32x2 x = {acc[m][n][rp * 2], acc[m][n][rp * 2 + 1]};
                    const f32x2 t2 = x * x;
                    f32x2 q = t2 * C4 + C3;
                    q = t2 * q + C2;
                    q = t2 * q + C1;
                    sh2 = t2 * q + sh2;
                    const int pp = pidp[m * 2 + rp];
                    const int cd = n ? chi : clo;
                    const f32x2 cc = {
                        ((pp & 0xffff) == cd) ? -0.5f : 0.5f,
                        ((pp >> 16)    == cd) ? -0.5f : 0.5f};
                    sx2 = x * cc + sx2;
                }
    };

#pragma unroll 1
    for (int t = 0; t < 7; ++t) tileBody(t, &sB[t][0]);   // vmem- & barrier-free

    __syncthreads();                 // tile-7 stage landed (issued ~7 tiles ago)
    tileBody(7, &sA[0]);

    // ---- block partial + fused deterministic reduction (last block) ----
    float lsum = sh2.x + sh2.y + sx2.x + sx2.y;
#pragma unroll
    for (int off = 32; off; off >>= 1) lsum += __shfl_xor(lsum, off, 64);
    if (lane == 0) bsums[wv] = lsum;
    __syncthreads();
    if (tid == 0) {
        float bs = 0.f;
#pragma unroll
        for (int w = 0; w < 8; ++w) bs += bsums[w];
        __hip_atomic_store(&partial[bid], bs, __ATOMIC_RELEASE, __HIP_MEMORY_SCOPE_AGENT);
        const unsigned old = __hip_atomic_fetch_add(counter, 1u, __ATOMIC_ACQ_REL,
                                                    __HIP_MEMORY_SCOPE_AGENT);
        amlast = (old == 255u);
    }
    __syncthreads();
    if (amlast) {
        double s = 0.0;
        if (tid < 256)
            s = (double)__hip_atomic_load(&partial[tid], __ATOMIC_ACQUIRE,
                                          __HIP_MEMORY_SCOPE_AGENT);
#pragma unroll
        for (int off = 32; off; off >>= 1) s += __shfl_xor(s, off, 64);
        if (lane == 0) red[wv] = s;
        __syncthreads();
        if (tid == 0) {
            double tot = 0.0;
#pragma unroll
            for (int w = 0; w < 8; ++w) tot += red[w];
            out[0] = (float)(tot * (1.0 / ((double)P * (double)C)) + 0.69314718055994531);
            __hip_atomic_store(counter, 0u, __ATOMIC_RELAXED, __HIP_MEMORY_SCOPE_AGENT);
        }
    }
}

extern "C" void kernel_launch(void* const* d_in, const int* in_sizes, int n_in,
                              void* d_out, int out_size, void* d_ws, size_t ws_size,
                              hipStream_t stream) {
    const float* prev_feat = (const float*)d_in[0];
    const float* cur_feat  = (const float*)d_in[1];
    const int* prev_ids    = (const int*)d_in[2];
    const int* cur_ids     = (const int*)d_in[3];
    float* out = (float*)d_out;

    char* ws = (char*)d_ws;
    unsigned char* prevb = (unsigned char*)ws;                            // 1 MB
    unsigned char* curb  = (unsigned char*)(ws + (size_t)P * DB);         // 1 MB
    float* partial = (float*)(ws + (size_t)(P + C) * DB);                 // 1 KB
    unsigned int* counter = (unsigned int*)(partial + 256);               // 4 B

    prep_kernel<<<(P + C) / 4, 256, 0, stream>>>(prev_feat, cur_feat, prevb, curb, counter);
    gemm_bce_kernel<<<256, 512, 0, stream>>>(prevb, curb, prev_ids, cur_ids,
                                             partial, counter, out);
}

// Round 20
// 37.601 us; speedup vs baseline: 1.0169x; 1.0169x over previous
//
#include <hip/hip_runtime.h>
#include <hip/hip_bf16.h>

typedef __attribute__((ext_vector_type(4))) float f32x4;
typedef __attribute__((ext_vector_type(2))) float f32x2;
typedef __attribute__((ext_vector_type(4))) int i32x4;
typedef __attribute__((ext_vector_type(8))) int i32x8;

constexpr int P = 8192, C = 8192, D = 256;
constexpr int DB = D / 2;   // 128 bytes per packed fp4 row

__device__ __forceinline__ void gload_lds16(const void* g, void* l) {
    __builtin_amdgcn_global_load_lds((const __attribute__((address_space(1))) void*)g,
                                     (__attribute__((address_space(3))) void*)l, 16, 0, 0);
}

// fp4 e2m1 RTN encode of t in +/-[0,6]; grid {0,.5,1,1.5,2,3,4,6}.
__device__ __forceinline__ unsigned int q4(float t) {
    const float a = fabsf(t);
    unsigned int c = (a >= 0.25f) + (a >= 0.75f) + (a >= 1.25f) + (a >= 1.75f)
                   + (a >= 2.5f) + (a >= 3.5f) + (a >= 5.0f);
    return c | (t < 0.f ? 8u : 0u);
}

// Normalize rows to unit L2, scale x8, store packed fp4 e2m1 (2/byte).
// Block 0 thread 0 zeroes the gemm's done-counter (ws poisoned once, never
// re-poisoned; stream order makes the zero visible to the gemm kernel).
__global__ __launch_bounds__(256) void prep_kernel(const float* __restrict__ prev,
                                                   const float* __restrict__ cur,
                                                   unsigned char* __restrict__ prevb,
                                                   unsigned char* __restrict__ curb,
                                                   unsigned int* __restrict__ counter) {
    if (blockIdx.x == 0 && threadIdx.x == 0)
        __hip_atomic_store(counter, 0u, __ATOMIC_RELAXED, __HIP_MEMORY_SCOPE_AGENT);
    const int lane = threadIdx.x & 63;
    const int wv = threadIdx.x >> 6;
    const int row = blockIdx.x * 4 + wv;
    const float* src;
    unsigned char* dst;
    int r;
    if (row < P) { src = prev; dst = prevb; r = row; }
    else         { src = cur;  dst = curb;  r = row - P; }
    const float4 v = *(const float4*)(src + (size_t)r * D + lane * 4);
    float ss = v.x * v.x + v.y * v.y + v.z * v.z + v.w * v.w;
#pragma unroll
    for (int off = 32; off; off >>= 1) ss += __shfl_xor(ss, off, 64);
    const float s8 = 8.0f / sqrtf(ss);
    const unsigned int b0 = q4(v.x * s8) | (q4(v.y * s8) << 4);
    const unsigned int b1 = q4(v.z * s8) | (q4(v.w * s8) << 4);
    ((unsigned short*)(dst + (size_t)r * DB))[lane] = (unsigned short)(b0 | (b1 << 8));
}

// fmt 4 = fp4 both operands; scale bytes 0x7C = 2^-3 (E8M0 124).
#define MFMA_SC4(A, B, ACC) \
    __builtin_amdgcn_mfma_scale_f32_16x16x128_f8f6f4( \
        (A), (B), (ACC), 4, 4, 0, 0x7C7C7C7C, 0, 0x7C7C7C7C)

// r18 stage-once fp4 GEMM, UNCHANGED per-wave code (cid loads per-tile, r18's
// proven register budget), plus ONLY the fused deterministic reduction:
// each block publishes its partial (agent-scope atomic store), last block
// (device counter) re-reads all 256 partials in FIXED order in double ->
// bitwise-deterministic, third launch eliminated. r19's regression is
// attributed to its cidp hoist (8 extra persistent regs, spill tip-over),
// which is NOT carried here.
__global__ __attribute__((amdgpu_flat_work_group_size(512, 512), amdgpu_waves_per_eu(2, 2)))
void gemm_bce_kernel(
    const unsigned char* __restrict__ Ab, const unsigned char* __restrict__ Bb,
    const int* __restrict__ pids, const int* __restrict__ cids,
    float* __restrict__ partial, unsigned int* __restrict__ counter,
    float* __restrict__ out) {
    __shared__ unsigned char sA[32768];        // 256 rows x 128 B; later tile-7 B
    __shared__ unsigned char sB[7][16384];     // 128 cols x 128 B per tile
    __shared__ float bsums[8];
    __shared__ double red[8];
    __shared__ int amlast;

    const int tid = threadIdx.x;
    const int lane = tid & 63;
    const int wv = tid >> 6;
    const int wm = wv >> 2, wn = wv & 3;       // 2M x 4N; wave tile 128x32
    const int fr = lane & 15, fq = lane >> 4;
    const int bid = blockIdx.x;
    const int cslab = (bid & 7) * 1024;        // XCD col-slab
    const int pblock = (bid >> 3) * 256;

    auto stageA = [&]() {
#pragma unroll
        for (int i = 0; i < 4; ++i) {
            const int G = i * 512 + tid;       // 2048 granules = 256 rows x 8
            const int row = G >> 3, g = G & 7;
            gload_lds16(Ab + (size_t)(pblock + row) * DB + ((g ^ (row & 7)) * 16),
                        &sA[G * 16]);
        }
    };
    auto stageB = [&](int t, unsigned char* dst) {
#pragma unroll
        for (int i = 0; i < 2; ++i) {
            const int G = i * 512 + tid;       // 1024 granules = 128 cols x 8
            const int col = G >> 3, g = G & 7;
            gload_lds16(Bb + (size_t)(cslab + t * 128 + col) * DB + ((g ^ (col & 7)) * 16),
                        dst + G * 16);
        }
    };

    // pids packed 2/reg: acc row = wm*128 + m*16 + fq*4 + reg.
    int pidp[16];
#pragma unroll
    for (int m = 0; m < 8; ++m)
#pragma unroll
        for (int rp = 0; rp < 2; ++rp) {
            const int base = pblock + wm * 128 + m * 16 + fq * 4 + rp * 2;
            pidp[m * 2 + rp] = (pids[base] & 0xffff) | (pids[base + 1] << 16);
        }

    stageA();
#pragma unroll
    for (int t = 0; t < 7; ++t) stageB(t, &sB[t][0]);
    __syncthreads();                 // ONE drain: ids + A + B0..6 all landed

    // ---- A fragments: LDS -> regs ONCE (payload lo half, hi duplicated) ----
    i32x8 afr[8][2];
#pragma unroll
    for (int m = 0; m < 8; ++m)
#pragma unroll
        for (int kt = 0; kt < 2; ++kt) {
            const int row = wm * 128 + m * 16 + fr;
            const int g = kt * 4 + fq;
            const i32x4 lo = *(const i32x4*)&sA[row * DB + ((g ^ (row & 7)) * 16)];
            afr[m][kt] = __builtin_shufflevector(lo, lo, 0, 1, 2, 3, 0, 1, 2, 3);
        }
    __syncthreads();                 // sA reads done -> safe to overwrite
    stageB(7, &sA[0]);               // tile 7 into dead sA (lands during t0..6)

    constexpr float C1 = 0.125f, C2 = -5.2083333e-3f, C3 = 3.4722222e-4f, C4 = -2.6354832e-5f;
    f32x2 sh2 = {0.f, 0.f}, sx2 = {0.f, 0.f};

    auto tileBody = [&](int t, const unsigned char* pb) {
        i32x8 bfr[2][2];
#pragma unroll
        for (int n = 0; n < 2; ++n)
#pragma unroll
            for (int kt = 0; kt < 2; ++kt) {
                const int col = wn * 32 + n * 16 + fr;
                const int g = kt * 4 + fq;
                const i32x4 lo = *(const i32x4*)&pb[col * DB + ((g ^ (col & 7)) * 16)];
                bfr[n][kt] = __builtin_shufflevector(lo, lo, 0, 1, 2, 3, 0, 1, 2, 3);
            }
        f32x4 acc[8][2] = {};
        __builtin_amdgcn_s_setprio(1);
#pragma unroll
        for (int kt = 0; kt < 2; ++kt)
#pragma unroll
            for (int m = 0; m < 8; ++m)
#pragma unroll
                for (int n = 0; n < 2; ++n)
                    acc[m][n] = MFMA_SC4(afr[m][kt], bfr[n][kt], acc[m][n]);
        __builtin_amdgcn_s_setprio(0);

        int cid_r[2];                          // per-tile, transient (r18 form)
#pragma unroll
        for (int n = 0; n < 2; ++n)
            cid_r[n] = cids[cslab + t * 128 + wn * 32 + n * 16 + fr];
        // fused BCE epilogue (C/D: col=lane&15, row=fq*4+reg, m89-verified)
#pragma unroll
        for (int m = 0; m < 8; ++m)
#pragma unroll
            for (int n = 0; n < 2; ++n)
#pragma unroll
                for (int rp = 0; rp < 2; ++rp) {
                    const f32x2 x = {acc[m][n][rp * 2], acc[m][n][rp * 2 + 1]};
                    const f32x2 t2 = x * x;
                    f32x2 q = t2 * C4 + C3;
                    q = t2 * q + C2;
                    q = t2 * q + C1;
                    sh2 = t2 * q + sh2;
                    const int pp = pidp[m * 2 + rp];
                    const f32x2 cc = {
                        ((pp & 0xffff) == cid_r[n]) ? -0.5f : 0.5f,
                        ((pp >> 16)    == cid_r[n]) ? -0.5f : 0.5f};
                    sx2 = x * cc + sx2;
                }
    };

#pragma unroll 1
    for (int t = 0; t < 7; ++t) tileBody(t, &sB[t][0]);   // barrier-free

    __syncthreads();                 // tile-7 stage landed (issued ~7 tiles ago)
    tileBody(7, &sA[0]);

    // ---- block partial + fused deterministic reduction (last block) ----
    float lsum = sh2.x + sh2.y + sx2.x + sx2.y;
#pragma unroll
    for (int off = 32; off; off >>= 1) lsum += __shfl_xor(lsum, off, 64);
    if (lane == 0) bsums[wv] = lsum;
    __syncthreads();
    if (tid == 0) {
        float bs = 0.f;
#pragma unroll
        for (int w = 0; w < 8; ++w) bs += bsums[w];
        __hip_atomic_store(&partial[bid], bs, __ATOMIC_RELEASE, __HIP_MEMORY_SCOPE_AGENT);
        const unsigned old = __hip_atomic_fetch_add(counter, 1u, __ATOMIC_ACQ_REL,
                                                    __HIP_MEMORY_SCOPE_AGENT);
        amlast = (old == 255u);
    }
    __syncthreads();
    if (amlast) {
        double s = 0.0;
        if (tid < 256)
            s = (double)__hip_atomic_load(&partial[tid], __ATOMIC_ACQUIRE,
                                          __HIP_MEMORY_SCOPE_AGENT);
#pragma unroll
        for (int off = 32; off; off >>= 1) s += __shfl_xor(s, off, 64);
        if (lane == 0) red[wv] = s;
        __syncthreads();
        if (tid == 0) {
            double tot = 0.0;
#pragma unroll
            for (int w = 0; w < 8; ++w) tot += red[w];
            out[0] = (float)(tot * (1.0 / ((double)P * (double)C)) + 0.69314718055994531);
        }
    }
}

extern "C" void kernel_launch(void* const* d_in, const int* in_sizes, int n_in,
                              void* d_out, int out_size, void* d_ws, size_t ws_size,
                              hipStream_t stream) {
    const float* prev_feat = (const float*)d_in[0];
    const float* cur_feat  = (const float*)d_in[1];
    const int* prev_ids    = (const int*)d_in[2];
    const int* cur_ids     = (const int*)d_in[3];
    float* out = (float*)d_out;

    char* ws = (char*)d_ws;
    unsigned char* prevb = (unsigned char*)ws;                            // 1 MB
    unsigned char* curb  = (unsigned char*)(ws + (size_t)P * DB);         // 1 MB
    float* partial = (float*)(ws + (size_t)(P + C) * DB);                 // 1 KB
    unsigned int* counter = (unsigned int*)(partial + 256);               // 4 B

    prep_kernel<<<(P + C) / 4, 256, 0, stream>>>(prev_feat, cur_feat, prevb, curb, counter);
    gemm_bce_kernel<<<256, 512, 0, stream>>>(prevb, curb, prev_ids, cur_ids,
                                             partial, counter, out);
}

// Round 21
// 34.848 us; speedup vs baseline: 1.0973x; 1.0790x over previous
//
#include <hip/hip_runtime.h>
#include <hip/hip_bf16.h>

typedef __attribute__((ext_vector_type(4))) float f32x4;
typedef __attribute__((ext_vector_type(2))) float f32x2;
typedef __attribute__((ext_vector_type(4))) int i32x4;
typedef __attribute__((ext_vector_type(8))) int i32x8;

constexpr int P = 8192, C = 8192, D = 256;
constexpr int DB = D / 2;   // 128 bytes per packed fp4 row

__device__ __forceinline__ void gload_lds16(const void* g, void* l) {
    __builtin_amdgcn_global_load_lds((const __attribute__((address_space(1))) void*)g,
                                     (__attribute__((address_space(3))) void*)l, 16, 0, 0);
}

// fp4 e2m1 RTN encode of t in +/-[0,6]; grid {0,.5,1,1.5,2,3,4,6}.
__device__ __forceinline__ unsigned int q4(float t) {
    const float a = fabsf(t);
    unsigned int c = (a >= 0.25f) + (a >= 0.75f) + (a >= 1.25f) + (a >= 1.75f)
                   + (a >= 2.5f) + (a >= 3.5f) + (a >= 5.0f);
    return c | (t < 0.f ? 8u : 0u);
}

// Normalize rows to unit L2, scale x8, store packed fp4 e2m1 (2/byte).
__global__ __launch_bounds__(256) void prep_kernel(const float* __restrict__ prev,
                                                   const float* __restrict__ cur,
                                                   unsigned char* __restrict__ prevb,
                                                   unsigned char* __restrict__ curb) {
    const int lane = threadIdx.x & 63;
    const int wv = threadIdx.x >> 6;
    const int row = blockIdx.x * 4 + wv;
    const float* src;
    unsigned char* dst;
    int r;
    if (row < P) { src = prev; dst = prevb; r = row; }
    else         { src = cur;  dst = curb;  r = row - P; }
    const float4 v = *(const float4*)(src + (size_t)r * D + lane * 4);
    float ss = v.x * v.x + v.y * v.y + v.z * v.z + v.w * v.w;
#pragma unroll
    for (int off = 32; off; off >>= 1) ss += __shfl_xor(ss, off, 64);
    const float s8 = 8.0f / sqrtf(ss);
    const unsigned int b0 = q4(v.x * s8) | (q4(v.y * s8) << 4);
    const unsigned int b1 = q4(v.z * s8) | (q4(v.w * s8) << 4);
    ((unsigned short*)(dst + (size_t)r * DB))[lane] = (unsigned short)(b0 | (b1 << 8));
}

// fmt 4 = fp4 both operands; scale bytes 0x7C = 2^-3 (E8M0 124).
#define MFMA_SC4(A, B, ACC) \
    __builtin_amdgcn_mfma_scale_f32_16x16x128_f8f6f4( \
        (A), (B), (ACC), 4, 4, 0, 0x7C7C7C7C, 0, 0x7C7C7C7C)

// FINAL (r18): STAGE-ONCE fp4 GEMM. Whole working set (A 32 KB + B0..6
// 112 KB) staged before ONE barrier; tile 7 staged into sA (dead after afr
// preload). Tiles 0..6 run with ZERO barriers / waitcnts / staging — pure
// {4 ds_read_b128 -> 32 MFMA-K128 -> VALU epilogue} per wave per tile.
// 256 blocks = 1/CU. Separate reduce kernel (fusion measured −4 µs, r20).
__global__ __attribute__((amdgpu_flat_work_group_size(512, 512), amdgpu_waves_per_eu(2, 2)))
void gemm_bce_kernel(
    const unsigned char* __restrict__ Ab, const unsigned char* __restrict__ Bb,
    const int* __restrict__ pids, const int* __restrict__ cids,
    float* __restrict__ partial) {
    __shared__ unsigned char sA[32768];        // 256 rows x 128 B; later tile-7 B
    __shared__ unsigned char sB[7][16384];     // 128 cols x 128 B per tile

    const int tid = threadIdx.x;
    const int lane = tid & 63;
    const int wv = tid >> 6;
    const int wm = wv >> 2, wn = wv & 3;       // 2M x 4N; wave tile 128x32
    const int fr = lane & 15, fq = lane >> 4;
    const int bid = blockIdx.x;
    const int cslab = (bid & 7) * 1024;        // XCD col-slab
    const int pblock = (bid >> 3) * 256;

    auto stageA = [&]() {
#pragma unroll
        for (int i = 0; i < 4; ++i) {
            const int G = i * 512 + tid;       // 2048 granules = 256 rows x 8
            const int row = G >> 3, g = G & 7;
            gload_lds16(Ab + (size_t)(pblock + row) * DB + ((g ^ (row & 7)) * 16),
                        &sA[G * 16]);
        }
    };
    auto stageB = [&](int t, unsigned char* dst) {
#pragma unroll
        for (int i = 0; i < 2; ++i) {
            const int G = i * 512 + tid;       // 1024 granules = 128 cols x 8
            const int col = G >> 3, g = G & 7;
            gload_lds16(Bb + (size_t)(cslab + t * 128 + col) * DB + ((g ^ (col & 7)) * 16),
                        dst + G * 16);
        }
    };

    // pids packed 2/reg: acc row = wm*128 + m*16 + fq*4 + reg.
    int pidp[16];
#pragma unroll
    for (int m = 0; m < 8; ++m)
#pragma unroll
        for (int rp = 0; rp < 2; ++rp) {
            const int base = pblock + wm * 128 + m * 16 + fq * 4 + rp * 2;
            pidp[m * 2 + rp] = (pids[base] & 0xffff) | (pids[base + 1] << 16);
        }

    stageA();
#pragma unroll
    for (int t = 0; t < 7; ++t) stageB(t, &sB[t][0]);
    __syncthreads();                 // ONE drain: ids + A + B0..6 all landed

    // ---- A fragments: LDS -> regs ONCE (payload lo half, hi duplicated) ----
    i32x8 afr[8][2];
#pragma unroll
    for (int m = 0; m < 8; ++m)
#pragma unroll
        for (int kt = 0; kt < 2; ++kt) {
            const int row = wm * 128 + m * 16 + fr;
            const int g = kt * 4 + fq;
            const i32x4 lo = *(const i32x4*)&sA[row * DB + ((g ^ (row & 7)) * 16)];
            afr[m][kt] = __builtin_shufflevector(lo, lo, 0, 1, 2, 3, 0, 1, 2, 3);
        }
    __syncthreads();                 // sA reads done -> safe to overwrite
    stageB(7, &sA[0]);               // tile 7 into dead sA (lands during t0..6)

    constexpr float C1 = 0.125f, C2 = -5.2083333e-3f, C3 = 3.4722222e-4f, C4 = -2.6354832e-5f;
    f32x2 sh2 = {0.f, 0.f}, sx2 = {0.f, 0.f};

    auto tileBody = [&](int t, const unsigned char* pb) {
        i32x8 bfr[2][2];
#pragma unroll
        for (int n = 0; n < 2; ++n)
#pragma unroll
            for (int kt = 0; kt < 2; ++kt) {
                const int col = wn * 32 + n * 16 + fr;
                const int g = kt * 4 + fq;
                const i32x4 lo = *(const i32x4*)&pb[col * DB + ((g ^ (col & 7)) * 16)];
                bfr[n][kt] = __builtin_shufflevector(lo, lo, 0, 1, 2, 3, 0, 1, 2, 3);
            }
        f32x4 acc[8][2] = {};
        __builtin_amdgcn_s_setprio(1);
#pragma unroll
        for (int kt = 0; kt < 2; ++kt)
#pragma unroll
            for (int m = 0; m < 8; ++m)
#pragma unroll
                for (int n = 0; n < 2; ++n)
                    acc[m][n] = MFMA_SC4(afr[m][kt], bfr[n][kt], acc[m][n]);
        __builtin_amdgcn_s_setprio(0);

        int cid_r[2];
#pragma unroll
        for (int n = 0; n < 2; ++n)
            cid_r[n] = cids[cslab + t * 128 + wn * 32 + n * 16 + fr];
        // fused BCE epilogue (C/D: col=lane&15, row=fq*4+reg, m89-verified)
#pragma unroll
        for (int m = 0; m < 8; ++m)
#pragma unroll
            for (int n = 0; n < 2; ++n)
#pragma unroll
                for (int rp = 0; rp < 2; ++rp) {
                    const f32x2 x = {acc[m][n][rp * 2], acc[m][n][rp * 2 + 1]};
                    const f32x2 t2 = x * x;
                    f32x2 q = t2 * C4 + C3;
                    q = t2 * q + C2;
                    q = t2 * q + C1;
                    sh2 = t2 * q + sh2;
                    const int pp = pidp[m * 2 + rp];
                    const f32x2 cc = {
                        ((pp & 0xffff) == cid_r[n]) ? -0.5f : 0.5f,
                        ((pp >> 16)    == cid_r[n]) ? -0.5f : 0.5f};
                    sx2 = x * cc + sx2;
                }
    };

#pragma unroll 1
    for (int t = 0; t < 7; ++t) tileBody(t, &sB[t][0]);   // barrier-free

    __syncthreads();                 // tile-7 stage landed (issued ~7 tiles ago)
    tileBody(7, &sA[0]);

    float lsum = sh2.x + sh2.y + sx2.x + sx2.y;
#pragma unroll
    for (int off = 32; off; off >>= 1) lsum += __shfl_xor(lsum, off, 64);
    if (lane == 0) partial[bid * 8 + wv] = lsum;   // per-wave partial, no LDS
}

// Deterministic final reduction over 2048 wave partials; adds folded ln2.
__global__ __launch_bounds__(256) void reduce_kernel(const float* __restrict__ part,
                                                     float* __restrict__ out) {
    const int tid = threadIdx.x;
    double s = 0.0;
    for (int i = tid; i < 2048; i += 256) s += (double)part[i];
#pragma unroll
    for (int off = 32; off; off >>= 1) s += __shfl_xor(s, off, 64);
    __shared__ double red[4];
    const int lane = tid & 63, wv = tid >> 6;
    if (lane == 0) red[wv] = s;
    __syncthreads();
    if (tid == 0)
        out[0] = (float)((red[0] + red[1] + red[2] + red[3]) * (1.0 / ((double)P * (double)C))
                         + 0.69314718055994531);
}

extern "C" void kernel_launch(void* const* d_in, const int* in_sizes, int n_in,
                              void* d_out, int out_size, void* d_ws, size_t ws_size,
                              hipStream_t stream) {
    const float* prev_feat = (const float*)d_in[0];
    const float* cur_feat  = (const float*)d_in[1];
    const int* prev_ids    = (const int*)d_in[2];
    const int* cur_ids     = (const int*)d_in[3];
    float* out = (float*)d_out;

    char* ws = (char*)d_ws;
    unsigned char* prevb = (unsigned char*)ws;                            // 1 MB
    unsigned char* curb  = (unsigned char*)(ws + (size_t)P * DB);         // 1 MB
    float* partial = (float*)(ws + (size_t)(P + C) * DB);                 // 8 KB

    prep_kernel<<<(P + C) / 4, 256, 0, stream>>>(prev_feat, cur_feat, prevb, curb);
    gemm_bce_kernel<<<256, 512, 0, stream>>>(prevb, curb, prev_ids, cur_ids, partial);
    reduce_kernel<<<1, 256, 0, stream>>>(partial, out);
}